// Round 12
// baseline (8415.293 us; speedup 1.0000x reference)
//
#include <hip/hip_runtime.h>
#include <math.h>

// Persistent cooperative 2-layer LSTM. Round 12: R11 (decoupled dataflow
// domains) + BUSY-POLL to defeat DPM downclocking. Theory: R8-R11 all land at
// ~16us/step because waves idle (s_sleep/barrier) ~95% of the time -> SMU
// drops SCLK to floor -> every latency in the produce->publish->consume chain
// inflates by the clock ratio. Fix: all 4 waves poll (lane l -> flag line l,
// distinct lines), with a dependent v_fmac_f32 chain between samples instead
// of s_sleep. Everything else byte-identical to R11 (passed, absmax 4.9e-4).
//
// B=64, T=512, D=128, H=512. 256 WGs x 256 threads (4 waves), 1 block/CU.
// WG w: bgrp = w&1, half = (w>>1)&1 (layer), cg = w>>2 (8 h-cols).
// 4 independent groups of 64 WGs: (bgrp, layer); single-hop flag protocol:
//  - L1 polls own F1 (h1(s-1)) and L0's F0 (h0(s) ready <=> F0>=s+2).
//  - L0 runs ahead (ring depth 4) with backpressure F1 >= t-2.
// Flag = 1 + steps completed. Ring slot for h(j) = (j+1)&3.
// Ring writes: 32-bit relaxed agent stores; reads: 64-bit relaxed agent
// atomic loads. Split precision MFMA: Whi*hhi + Whi*hlo + Wlo*hhi.
//
// ws layout (bytes): flags[4][64] lines @0 (16KB); uints @20480:
//   r0h[4][64][256], r0l, r1h, r1l (256KB each plane, 1MB total).

#define TT 512
#define NWG 256

typedef __attribute__((ext_vector_type(8))) short short8;
typedef __attribute__((ext_vector_type(4))) float f32x4;

// red[khalf][m 0..31][n 0..31 pad 35]
#define RED(K,M,N) ((((K)*32+(M))*35)+(N))
#define RED_TOT (2*32*35)

__device__ __forceinline__ float fsigmoid(float v){ return 1.f/(1.f+__expf(-v)); }
__device__ __forceinline__ float ftanh(float v){ return 2.f/(1.f+__expf(-2.f*v)) - 1.f; }

__device__ __forceinline__ unsigned short f2bf(float f){
  unsigned u = __float_as_uint(f);
  unsigned r = ((u>>16)&1u) + 0x7FFFu;
  return (unsigned short)((u + r)>>16);
}
__device__ __forceinline__ float bf2f(unsigned short s){
  return __uint_as_float(((unsigned)s)<<16);
}
__device__ __forceinline__ void cvt8(const float4& a, const float4& b,
                                     short8& hi, short8& lo){
  float v[8] = {a.x,a.y,a.z,a.w,b.x,b.y,b.z,b.w};
  #pragma unroll
  for (int i=0;i<8;i++){
    unsigned short h = f2bf(v[i]);
    unsigned short l = f2bf(v[i] - bf2f(h));
    ((unsigned short*)&hi)[i] = h;
    ((unsigned short*)&lo)[i] = l;
  }
}

__device__ __forceinline__ void st_agent_f(float* p, float v){
  __hip_atomic_store(p, v, __ATOMIC_RELAXED, __HIP_MEMORY_SCOPE_AGENT);
}
__device__ __forceinline__ void st_agent_u32(unsigned* p, unsigned v){
  __hip_atomic_store(p, v, __ATOMIC_RELAXED, __HIP_MEMORY_SCOPE_AGENT);
}
__device__ __forceinline__ unsigned ldflag(const unsigned* p){
  return __hip_atomic_load(p, __ATOMIC_RELAXED, __HIP_MEMORY_SCOPE_AGENT);
}

// Busy-wait filler: dependent VALU chain (~120 cycles). Keeps the CU's VALU
// pipes visibly busy so the SMU holds high SCLK; asm volatile -> not DCE'd.
__device__ __forceinline__ void spin_fma(float& z){
  #pragma unroll
  for (int i=0;i<24;i++)
    asm volatile("v_fmac_f32 %0, %1, %1" : "+v"(z) : "v"(z));
}

// Coherent 16B ring read: two 64-bit relaxed agent atomic loads (proven R10).
__device__ __forceinline__ short8 ld_ring16(const unsigned* p){
  const unsigned long long* q = (const unsigned long long*)p;
  union { unsigned long long u[2]; short8 s; } v;
  v.u[0] = __hip_atomic_load(&q[0], __ATOMIC_RELAXED, __HIP_MEMORY_SCOPE_AGENT);
  v.u[1] = __hip_atomic_load(&q[1], __ATOMIC_RELAXED, __HIP_MEMORY_SCOPE_AGENT);
  return v.s;
}
__device__ __forceinline__ void ld_ring16_u(const unsigned* p, unsigned o[4]){
  const unsigned long long* q = (const unsigned long long*)p;
  unsigned long long a = __hip_atomic_load(&q[0], __ATOMIC_RELAXED, __HIP_MEMORY_SCOPE_AGENT);
  unsigned long long b = __hip_atomic_load(&q[1], __ATOMIC_RELAXED, __HIP_MEMORY_SCOPE_AGENT);
  o[0] = (unsigned)a; o[1] = (unsigned)(a>>32);
  o[2] = (unsigned)b; o[3] = (unsigned)(b>>32);
}

// Gate MFMA loop; ring A-frags via agent atomic loads, x via LDS stage.
template<int KFC, int LAYER, int KHALF>
__device__ __forceinline__ void gates_mfma(
    const unsigned* __restrict__ rAh, const unsigned* __restrict__ rAl,
    const unsigned* __restrict__ rBh, const unsigned* __restrict__ rBl,
    const unsigned* xsh_t, const unsigned* xsl_t,
    const unsigned short* wh, const unsigned short* wlo,
    int m0, int m1, int kslot, int nidx,
    f32x4& acc0, f32x4& acc1)
{
  constexpr int KB = LAYER ? (KHALF*512) : (KHALF*320);
  #pragma unroll
  for (int kf=0; kf<KFC; ++kf){
    short8 a0h,a0l,a1h,a1l;
    if (LAYER==0 && KHALF==1 && kf>=6){
      int d2 = (kf-6)*16 + kslot*4;          // uint offset within x row
      a0h = *(const short8*)(xsh_t + (m0&31)*68 + d2);
      a0l = *(const short8*)(xsl_t + (m0&31)*68 + d2);
      a1h = *(const short8*)(xsh_t + (m1&31)*68 + d2);
      a1l = *(const short8*)(xsl_t + (m1&31)*68 + d2);
    } else {
      int kk = KB + kf*32 + kslot*8;
      const unsigned *bh, *bl; int k2;
      if (LAYER==1 && KHALF==1){ bh = rBh; bl = rBl; k2 = (kk-512)>>1; }
      else                     { bh = rAh; bl = rAl; k2 = kk>>1;       }
      a0h = ld_ring16(bh + m0*256 + k2);
      a0l = ld_ring16(bl + m0*256 + k2);
      a1h = ld_ring16(bh + m1*256 + k2);
      a1l = ld_ring16(bl + m1*256 + k2);
    }
    int c = ((KHALF*KFC + kf)*4 + kslot)*32 + nidx;
    short8 bhW = *(const short8*)(wh  + (size_t)c*8);
    short8 blW = *(const short8*)(wlo + (size_t)c*8);
    acc0 = __builtin_amdgcn_mfma_f32_16x16x32_bf16(a0h, bhW, acc0, 0,0,0);
    acc0 = __builtin_amdgcn_mfma_f32_16x16x32_bf16(a0l, bhW, acc0, 0,0,0);
    acc0 = __builtin_amdgcn_mfma_f32_16x16x32_bf16(a0h, blW, acc0, 0,0,0);
    acc1 = __builtin_amdgcn_mfma_f32_16x16x32_bf16(a1h, bhW, acc1, 0,0,0);
    acc1 = __builtin_amdgcn_mfma_f32_16x16x32_bf16(a1l, bhW, acc1, 0,0,0);
    acc1 = __builtin_amdgcn_mfma_f32_16x16x32_bf16(a1h, blW, acc1, 0,0,0);
  }
}

__global__ __launch_bounds__(256, 1) void lstm_pers(
    const float* __restrict__ x,    const float* __restrict__ h0in, const float* __restrict__ c0in,
    const float* __restrict__ wih0, const float* __restrict__ whh0,
    const float* __restrict__ bih0, const float* __restrict__ bhh0,
    const float* __restrict__ wih1, const float* __restrict__ whh1,
    const float* __restrict__ bih1, const float* __restrict__ bhh1,
    const float* __restrict__ wlin, const float* __restrict__ blin,
    float* __restrict__ out, float* ws)
{
  __shared__ __align__(16) unsigned short wlds_hi[32768];   // 65,536 B
  __shared__ __align__(16) unsigned short wlds_lo[32768];   // 65,536 B
  __shared__ __align__(16) float red[RED_TOT];              //  8,960 B
  const int tid = threadIdx.x, wg = blockIdx.x;
  const int lane = tid & 63;
  const int wid  = tid >> 6;
  const int bgrp = wg & 1;
  const int half = (wg >> 1) & 1;      // 0: layer0, 1: layer1
  const int cg   = wg >> 2;            // 0..63
  const int colbase = cg*8;
  const int khalf = wid & 1;
  const int ntile = wid >> 1;

  unsigned* flags = (unsigned*)ws;                  // 4 domains x 64 lines
  unsigned* F0 = flags + (bgrp*2 + 0)*64*16;        // this bgrp's L0 flags
  unsigned* F1 = flags + (bgrp*2 + 1)*64*16;        // this bgrp's L1 flags
  unsigned* myF = half ? F1 : F0;
  unsigned* r0h = ((unsigned*)ws) + 5120;           // [4][64][256] each plane
  unsigned* r0l = r0h + 65536;
  unsigned* r1h = r0h + 131072;
  unsigned* r1l = r0h + 196608;

  unsigned* xsh_s = (unsigned*)(wlds_hi + 20480);   // L0 WGs only (overlay)
  unsigned* xsl_s = (unsigned*)(wlds_lo + 20480);

  // ---- W (bf16 hi/lo) into LDS, once. chunk c = ((kh*KFC+kf)*4+ks)*32+n ----
  if (half == 0){
    for (int c = tid; c < 2560; c += 256){
      int kh = c / 1280; int rem = c - kh*1280;
      int kf = rem >> 7; int rem2 = rem & 127;
      int ks = rem2 >> 5; int n = rem2 & 31;
      int kk = kh*320 + kf*32 + ks*8;
      int wrow = (n>>3)*512 + colbase + (n&7);
      const float* src; long off;
      if (kk < 512){ src = whh0; off = (long)wrow*512 + kk; }
      else         { src = wih0; off = (long)wrow*128 + (kk-512); }
      float4 a = *(const float4*)(src + off);
      float4 b = *(const float4*)(src + off + 4);
      short8 hi, lo; cvt8(a, b, hi, lo);
      *(short8*)(wlds_hi + (size_t)c*8) = hi;
      *(short8*)(wlds_lo + (size_t)c*8) = lo;
    }
  } else {
    for (int c = tid; c < 4096; c += 256){
      int kh = c >> 11; int rem = c & 2047;
      int kf = rem >> 7; int rem2 = rem & 127;
      int ks = rem2 >> 5; int n = rem2 & 31;
      int kk = kh*512 + kf*32 + ks*8;
      int wrow = (n>>3)*512 + colbase + (n&7);
      const float* src; long off;
      if (kk < 512){ src = whh1; off = (long)wrow*512 + kk; }
      else         { src = wih1; off = (long)wrow*512 + (kk-512); }
      float4 a = *(const float4*)(src + off);
      float4 b = *(const float4*)(src + off + 4);
      short8 hi, lo; cvt8(a, b, hi, lo);
      *(short8*)(wlds_hi + (size_t)c*8) = hi;
      *(short8*)(wlds_lo + (size_t)c*8) = lo;
    }
  }

  // ---- activation-role state: 1 cell/thread, this WG's layer ----
  const int m_l = tid >> 3;            // 0..31 local batch
  const int cl  = tid & 7;             // 0..7 local col
  const int col_own = colbase + cl;
  const int bb_a = bgrp*32 + m_l;
  float biasr[4], cst;
  #pragma unroll
  for (int g=0; g<4; ++g){
    biasr[g] = half ? (bih1[g*512+col_own] + bhh1[g*512+col_own])
                    : (bih0[g*512+col_own] + bhh0[g*512+col_own]);
  }
  cst = c0in[half*32768 + bb_a*512 + col_own];
  float blin_r = blin[0];

  // ---- y-role state: lane holds wlin[8k..8k+8) ----
  float wl[8];
  {
    const float4* wp = (const float4*)wlin + (lane*2);
    float4 w0 = wp[0], w1 = wp[1];
    wl[0]=w0.x; wl[1]=w0.y; wl[2]=w0.z; wl[3]=w0.w;
    wl[4]=w1.x; wl[5]=w1.y; wl[6]=w1.z; wl[7]=w1.w;
  }

  // ---- init h(-1) into ring slot 0, DOMAIN-RESTRICTED (own bgrp+layer) ----
  {
    int e = cg*256 + tid;                  // [0, 16384) within (half,bgrp) slab
    if (!(e & 1)){
      int m = e >> 9;                      // 0..31 local batch
      int col = e & 511;
      const float* src = h0in + half*32768 + (size_t)(bgrp*32+m)*512 + col;
      float v0 = src[0], v1 = src[1];
      unsigned short hA = f2bf(v0), lA = f2bf(v0 - bf2f(hA));
      unsigned short hB = f2bf(v1), lB = f2bf(v1 - bf2f(hB));
      unsigned uh = (unsigned)hA | ((unsigned)hB<<16);
      unsigned ul = (unsigned)lA | ((unsigned)lB<<16);
      int idx2 = (bgrp*32+m)*256 + (col>>1);     // slot 0
      unsigned* ph = half ? r1h : r0h;
      unsigned* pl = half ? r1l : r0l;
      st_agent_u32(ph + idx2, uh);
      st_agent_u32(pl + idx2, ul);
    }
  }

  // ---- x stage for t=0 (L0 WGs, LDS-local) ----
  if (half == 0){
    int m = tid>>3, dd = (tid&7)*16;
    const float* xp = x + ((size_t)(bgrp*32+m))*65536 + 0*128 + dd;
    float4 v0 = *(const float4*)xp,      v1 = *(const float4*)(xp+4),
           v2 = *(const float4*)(xp+8),  v3 = *(const float4*)(xp+12);
    float vv[16] = {v0.x,v0.y,v0.z,v0.w, v1.x,v1.y,v1.z,v1.w,
                    v2.x,v2.y,v2.z,v2.w, v3.x,v3.y,v3.z,v3.w};
    unsigned uh[8], ul[8];
    #pragma unroll
    for (int j=0;j<8;j++){
      unsigned short hA = f2bf(vv[2*j]),   hB = f2bf(vv[2*j+1]);
      unsigned short lA = f2bf(vv[2*j]-bf2f(hA)), lB = f2bf(vv[2*j+1]-bf2f(hB));
      uh[j] = (unsigned)hA | ((unsigned)hB<<16);
      ul[j] = (unsigned)lA | ((unsigned)lB<<16);
    }
    unsigned* dh = xsh_s + m*68 + (dd>>1);
    unsigned* dl = xsl_s + m*68 + (dd>>1);
    *(uint4*)dh     = make_uint4(uh[0],uh[1],uh[2],uh[3]);
    *(uint4*)(dh+4) = make_uint4(uh[4],uh[5],uh[6],uh[7]);
    *(uint4*)dl     = make_uint4(ul[0],ul[1],ul[2],ul[3]);
    *(uint4*)(dl+4) = make_uint4(ul[4],ul[5],ul[6],ul[7]);
  }

  // publish init: flag = 1
  asm volatile("s_waitcnt vmcnt(0)" ::: "memory");
  __syncthreads();
  if (tid == 0) st_agent_u32(&myF[cg*16], 1u);

  const int m0 = bgrp*32 + (lane & 15);
  const int m1 = m0 + 16;
  const int kslot = lane >> 4;
  const int nidx  = ntile*16 + (lane & 15);
  float zspin = 1e-30f;

  if (half == 0){
    // ================= LAYER-0 GROUP: 512 dense steps =================
    for (int t = 0; t < TT; ++t){
      // poll (ALL 4 waves; lane l -> flag l; VALU busy-spin between samples):
      // own h0(t-1) ready (F0>=t+1); backpressure F1>=t-2 (t>=4).
      {
        const unsigned need0 = (unsigned)(t+1);
        const bool bp = (t >= 4);
        const unsigned need1 = (unsigned)(t-2);
        for(;;){
          bool ok = ldflag(&F0[lane*16]) >= need0;
          if (bp) ok &= (ldflag(&F1[lane*16]) >= need1);
          if (__all(ok)) break;
          spin_fma(zspin);
        }
      }
      __syncthreads();

      const unsigned* rAh = r0h + (t&3)*16384;       // h0(t-1)
      const unsigned* rAl = r0l + (t&3)*16384;
      const unsigned* xsh_t = xsh_s + (t&1)*2176;
      const unsigned* xsl_t = xsl_s + (t&1)*2176;
      f32x4 acc0 = {0.f,0.f,0.f,0.f}, acc1 = {0.f,0.f,0.f,0.f};
      if (khalf == 0) gates_mfma<10,0,0>(rAh,rAl,0,0,xsh_t,xsl_t,wlds_hi,wlds_lo,m0,m1,kslot,nidx,acc0,acc1);
      else            gates_mfma<10,0,1>(rAh,rAl,0,0,xsh_t,xsl_t,wlds_hi,wlds_lo,m0,m1,kslot,nidx,acc0,acc1);
      #pragma unroll
      for (int r=0; r<4; ++r){
        int mm = kslot*4 + r;
        red[RED(khalf, mm,    nidx)] = acc0[r];
        red[RED(khalf, 16+mm, nidx)] = acc1[r];
      }
      __syncthreads();

      // activation -> h0(t) into slot (t+1)&3
      {
        float g4[4];
        #pragma unroll
        for (int g=0; g<4; ++g){
          int n = g*8 + cl;
          g4[g] = red[RED(0,m_l,n)] + red[RED(1,m_l,n)] + biasr[g];
        }
        float gi = fsigmoid(g4[0]);
        float gf = fsigmoid(g4[1]);
        float gg = ftanh   (g4[2]);
        float go = fsigmoid(g4[3]);
        float c = gf*cst + gi*gg;
        cst = c;
        float h = go * ftanh(c);
        float h_oth = __shfl_xor(h, 1, 64);
        if (!(tid & 1)){
          unsigned short hA = f2bf(h),     lA = f2bf(h - bf2f(hA));
          unsigned short hB = f2bf(h_oth), lB = f2bf(h_oth - bf2f(hB));
          unsigned uh = (unsigned)hA | ((unsigned)hB<<16);
          unsigned ul = (unsigned)lA | ((unsigned)lB<<16);
          int off = ((t+1)&3)*16384 + bb_a*256 + (col_own>>1);
          st_agent_u32(r0h + off, uh);
          st_agent_u32(r0l + off, ul);
        }
      }
      asm volatile("s_waitcnt vmcnt(0)" ::: "memory");
      __syncthreads();
      if (tid == 0) st_agent_u32(&F0[cg*16], (unsigned)(t+2));

      // stage x(t+1) (LDS-local; ordered vs next read by next poll's sync)
      if (t+1 < TT){
        int m = tid>>3, dd = (tid&7)*16;
        const float* xp = x + ((size_t)(bgrp*32+m))*65536 + (size_t)(t+1)*128 + dd;
        float4 v0 = *(const float4*)xp,      v1 = *(const float4*)(xp+4),
               v2 = *(const float4*)(xp+8),  v3 = *(const float4*)(xp+12);
        float vv[16] = {v0.x,v0.y,v0.z,v0.w, v1.x,v1.y,v1.z,v1.w,
                        v2.x,v2.y,v2.z,v2.w, v3.x,v3.y,v3.z,v3.w};
        unsigned uh[8], ul[8];
        #pragma unroll
        for (int j=0;j<8;j++){
          unsigned short hA = f2bf(vv[2*j]),   hB = f2bf(vv[2*j+1]);
          unsigned short lA = f2bf(vv[2*j]-bf2f(hA)), lB = f2bf(vv[2*j+1]-bf2f(hB));
          uh[j] = (unsigned)hA | ((unsigned)hB<<16);
          ul[j] = (unsigned)lA | ((unsigned)lB<<16);
        }
        unsigned* dh = xsh_s + ((t+1)&1)*2176 + m*68 + (dd>>1);
        unsigned* dl = xsl_s + ((t+1)&1)*2176 + m*68 + (dd>>1);
        *(uint4*)dh     = make_uint4(uh[0],uh[1],uh[2],uh[3]);
        *(uint4*)(dh+4) = make_uint4(uh[4],uh[5],uh[6],uh[7]);
        *(uint4*)dl     = make_uint4(ul[0],ul[1],ul[2],ul[3]);
        *(uint4*)(dl+4) = make_uint4(ul[4],ul[5],ul[6],ul[7]);
      }
    }
  } else {
    // ================= LAYER-1 GROUP: 512 dense steps =================
    for (int s = 0; s < TT; ++s){
      // poll (ALL 4 waves): own h1(s-1) (F1>=s+1) AND h0(s) (F0>=s+2).
      {
        const unsigned need1 = (unsigned)(s+1);
        const unsigned need0 = (unsigned)(s+2);
        for(;;){
          bool ok = (ldflag(&F1[lane*16]) >= need1)
                  & (ldflag(&F0[lane*16]) >= need0);
          if (__all(ok)) break;
          spin_fma(zspin);
        }
      }
      __syncthreads();

      // y(s-2): h1(s-2) fully visible (F1>=s+1 > s-1). Slot (s-1)&3.
      if (s >= 2 && cg < 32 && wid == 0){
        int j = s - 2;
        int yb = bgrp*32 + cg;
        unsigned a4[4], b4[4];
        ld_ring16_u(r1h + ((s-1)&3)*16384 + yb*256 + lane*4, a4);
        ld_ring16_u(r1l + ((s-1)&3)*16384 + yb*256 + lane*4, b4);
        float p = 0.f;
        #pragma unroll
        for (int q=0;q<4;q++){
          unsigned qa=a4[q], qb=b4[q];
          float e0 = __uint_as_float(qa<<16) + __uint_as_float(qb<<16);
          float e1 = __uint_as_float(qa & 0xFFFF0000u) + __uint_as_float(qb & 0xFFFF0000u);
          p += e0*wl[2*q] + e1*wl[2*q+1];
        }
        #pragma unroll
        for (int m=1; m<64; m<<=1) p += __shfl_xor(p, m, 64);
        if (lane == 0) st_agent_f(&out[yb*512 + j], p + blin_r);
      }

      const unsigned* rAh = r1h + (s&3)*16384;       // h1(s-1)
      const unsigned* rAl = r1l + (s&3)*16384;
      const unsigned* rBh = r0h + ((s+1)&3)*16384;   // h0(s)
      const unsigned* rBl = r0l + ((s+1)&3)*16384;
      f32x4 acc0 = {0.f,0.f,0.f,0.f}, acc1 = {0.f,0.f,0.f,0.f};
      if (khalf == 0) gates_mfma<16,1,0>(rAh,rAl,rBh,rBl,0,0,wlds_hi,wlds_lo,m0,m1,kslot,nidx,acc0,acc1);
      else            gates_mfma<16,1,1>(rAh,rAl,rBh,rBl,0,0,wlds_hi,wlds_lo,m0,m1,kslot,nidx,acc0,acc1);
      #pragma unroll
      for (int r=0; r<4; ++r){
        int mm = kslot*4 + r;
        red[RED(khalf, mm,    nidx)] = acc0[r];
        red[RED(khalf, 16+mm, nidx)] = acc1[r];
      }
      __syncthreads();

      // activation -> h1(s) into slot (s+1)&3
      {
        float g4[4];
        #pragma unroll
        for (int g=0; g<4; ++g){
          int n = g*8 + cl;
          g4[g] = red[RED(0,m_l,n)] + red[RED(1,m_l,n)] + biasr[g];
        }
        float gi = fsigmoid(g4[0]);
        float gf = fsigmoid(g4[1]);
        float gg = ftanh   (g4[2]);
        float go = fsigmoid(g4[3]);
        float c = gf*cst + gi*gg;
        cst = c;
        float h = go * ftanh(c);
        float h_oth = __shfl_xor(h, 1, 64);
        if (!(tid & 1)){
          unsigned short hA = f2bf(h),     lA = f2bf(h - bf2f(hA));
          unsigned short hB = f2bf(h_oth), lB = f2bf(h_oth - bf2f(hB));
          unsigned uh = (unsigned)hA | ((unsigned)hB<<16);
          unsigned ul = (unsigned)lA | ((unsigned)lB<<16);
          int off = ((s+1)&3)*16384 + bb_a*256 + (col_own>>1);
          st_agent_u32(r1h + off, uh);
          st_agent_u32(r1l + off, ul);
        }
      }
      asm volatile("s_waitcnt vmcnt(0)" ::: "memory");
      __syncthreads();
      if (tid == 0) st_agent_u32(&F1[cg*16], (unsigned)(s+2));
    }

    // epilogue: wait for all h1(511), then y(510), y(511)
    {
      const unsigned need = (unsigned)(TT+1);
      while (ldflag(&F1[lane*16]) < need) spin_fma(zspin);
    }
    __syncthreads();
    if (cg < 32 && wid == 0){
      #pragma unroll
      for (int e=0; e<2; ++e){
        int j = TT-2+e;                       // 510, 511
        int yb = bgrp*32 + cg;
        unsigned a4[4], b4[4];
        ld_ring16_u(r1h + ((j+1)&3)*16384 + yb*256 + lane*4, a4);
        ld_ring16_u(r1l + ((j+1)&3)*16384 + yb*256 + lane*4, b4);
        float p = 0.f;
        #pragma unroll
        for (int q=0;q<4;q++){
          unsigned qa=a4[q], qb=b4[q];
          float e0 = __uint_as_float(qa<<16) + __uint_as_float(qb<<16);
          float e1 = __uint_as_float(qa & 0xFFFF0000u) + __uint_as_float(qb & 0xFFFF0000u);
          p += e0*wl[2*q] + e1*wl[2*q+1];
        }
        #pragma unroll
        for (int m=1; m<64; m<<=1) p += __shfl_xor(p, m, 64);
        if (lane == 0) st_agent_f(&out[yb*512 + j], p + blin_r);
      }
    }
  }
  // keep spin register live (prevents any clever DCE of the asm chain inputs)
  asm volatile("" :: "v"(zspin));
}

extern "C" void kernel_launch(void* const* d_in, const int* in_sizes, int n_in,
                              void* d_out, int out_size, void* d_ws, size_t ws_size,
                              hipStream_t stream)
{
  (void)in_sizes; (void)n_in; (void)out_size; (void)ws_size;
  const float* x    = (const float*)d_in[0];
  const float* h0   = (const float*)d_in[1];
  const float* c0   = (const float*)d_in[2];
  const float* wih0 = (const float*)d_in[3];
  const float* whh0 = (const float*)d_in[4];
  const float* bih0 = (const float*)d_in[5];
  const float* bhh0 = (const float*)d_in[6];
  const float* wih1 = (const float*)d_in[7];
  const float* whh1 = (const float*)d_in[8];
  const float* bih1 = (const float*)d_in[9];
  const float* bhh1 = (const float*)d_in[10];
  const float* wlin = (const float*)d_in[11];
  const float* blin = (const float*)d_in[12];
  float* outp = (float*)d_out;
  float* wsp  = (float*)d_ws;

  // zero flag lines; rings fully rewritten by the kernel each launch
  hipMemsetAsync(d_ws, 0, 18432, stream);

  void* args[] = { &x, &h0, &c0, &wih0, &whh0, &bih0, &bhh0,
                   &wih1, &whh1, &bih1, &bhh1, &wlin, &blin, &outp, &wsp };
  hipError_t err = hipLaunchCooperativeKernel((const void*)lstm_pers,
                                              dim3(NWG), dim3(256), args, 0, stream);
  if (err != hipSuccess){
    // Fallback: 1 block/CU (140KB LDS), 256 blocks on 256 CUs -> co-resident.
    hipLaunchKernelGGL(lstm_pers, dim3(NWG), dim3(256), 0, stream,
                       x, h0, c0, wih0, whh0, bih0, bhh0,
                       wih1, whh1, bih1, bhh1, wlin, blin, outp, wsp);
  }
}

// Round 13
// 7111.732 us; speedup vs baseline: 1.1833x; 1.1833x over previous
//
#include <hip/hip_runtime.h>
#include <math.h>

// Persistent cooperative 2-layer LSTM. Round 13: FRAGMENT-MAJOR ring layout
// (coalesced consumer loads) + clock-probe dispatch.
// Theory: R8-R12's invariant 15us/step floor is the scattered A-fragment
// gather (row-major ring -> 64 lines/load-instr, 16B useful per line). New
// ring layout stores h in MFMA fragment order: [chunk c>>5][sub b>>4]
// [lane=(b&15)|(((c>>3)&3)<<4)][8 bf16], so an A-frag load is base+lane*16 -
// dense coalesced b128. Ring reads become PLAIN b128 loads; coherence via the
// R9-proven per-step agent-acquire fence (R10: fence cost ~0). Stores remain
// agent write-through (never dirty -> inv-safe). Arithmetic bit-identical.
// Structure otherwise = R11 (decoupled (bgrp,layer) domains, single-hop
// flags, L0 runs ahead depth-4, backpressure F1>=t-2).
//
// clock_probe: separate 1-WG dispatch, 240K-cycle dependent v_fmac chain ->
// its rocprof dur reads true SCLK (100us @ 2.4GHz).
//
// ws layout (bytes): flags[4][64] lines @0 (16KB); probe sink @18432;
// uints @20480: r0h[4][2][8192B], r0l, r1h, r1l (256KB per plane, 1MB).

#define TT 512
#define NWG 256

typedef __attribute__((ext_vector_type(8))) short short8;
typedef __attribute__((ext_vector_type(4))) float f32x4;

#define RED(K,M,N) ((((K)*32+(M))*35)+(N))
#define RED_TOT (2*32*35)

__device__ __forceinline__ float fsigmoid(float v){ return 1.f/(1.f+__expf(-v)); }
__device__ __forceinline__ float ftanh(float v){ return 2.f/(1.f+__expf(-2.f*v)) - 1.f; }

__device__ __forceinline__ unsigned short f2bf(float f){
  unsigned u = __float_as_uint(f);
  unsigned r = ((u>>16)&1u) + 0x7FFFu;
  return (unsigned short)((u + r)>>16);
}
__device__ __forceinline__ float bf2f(unsigned short s){
  return __uint_as_float(((unsigned)s)<<16);
}
__device__ __forceinline__ void cvt8(const float4& a, const float4& b,
                                     short8& hi, short8& lo){
  float v[8] = {a.x,a.y,a.z,a.w,b.x,b.y,b.z,b.w};
  #pragma unroll
  for (int i=0;i<8;i++){
    unsigned short h = f2bf(v[i]);
    unsigned short l = f2bf(v[i] - bf2f(h));
    ((unsigned short*)&hi)[i] = h;
    ((unsigned short*)&lo)[i] = l;
  }
}

__device__ __forceinline__ void st_agent_f(float* p, float v){
  __hip_atomic_store(p, v, __ATOMIC_RELAXED, __HIP_MEMORY_SCOPE_AGENT);
}
__device__ __forceinline__ void st_agent_u32(unsigned* p, unsigned v){
  __hip_atomic_store(p, v, __ATOMIC_RELAXED, __HIP_MEMORY_SCOPE_AGENT);
}
__device__ __forceinline__ unsigned ldflag(const unsigned* p){
  return __hip_atomic_load(p, __ATOMIC_RELAXED, __HIP_MEMORY_SCOPE_AGENT);
}

// Gate MFMA loop. A-frags: PLAIN coalesced short8 loads from fragment-major
// ring slabs (lane-dense: slab + (chunk*2+sub)*256 + lane*4 uints).
template<int KFC, int LAYER, int KHALF>
__device__ __forceinline__ void gates_mfma(
    const unsigned* __restrict__ rAh, const unsigned* __restrict__ rAl,
    const unsigned* __restrict__ rBh, const unsigned* __restrict__ rBl,
    const unsigned* xsh_t, const unsigned* xsl_t,
    const unsigned short* wh, const unsigned short* wlo,
    int lane, int m0loc, int kslot, int nidx,
    f32x4& acc0, f32x4& acc1)
{
  constexpr int CB = LAYER ? 0 : (KHALF*10);   // chunk base (KB>>5)
  #pragma unroll
  for (int kf=0; kf<KFC; ++kf){
    short8 a0h,a0l,a1h,a1l;
    if (LAYER==0 && KHALF==1 && kf>=6){
      int d2 = (kf-6)*16 + kslot*4;          // uint offset within x row
      a0h = *(const short8*)(xsh_t + m0loc*68 + d2);
      a0l = *(const short8*)(xsl_t + m0loc*68 + d2);
      a1h = *(const short8*)(xsh_t + (m0loc+16)*68 + d2);
      a1l = *(const short8*)(xsl_t + (m0loc+16)*68 + d2);
    } else {
      const unsigned *bh, *bl;
      int chunk;
      if (LAYER==1 && KHALF==1){ bh = rBh; bl = rBl; chunk = kf; }
      else                     { bh = rAh; bl = rAl; chunk = CB + kf; }
      int o0 = chunk*512 + lane*4;           // sub 0 (rows 0..15)
      a0h = *(const short8*)(bh + o0);
      a0l = *(const short8*)(bl + o0);
      a1h = *(const short8*)(bh + o0 + 256); // sub 1 (rows 16..31)
      a1l = *(const short8*)(bl + o0 + 256);
    }
    int c = ((KHALF*KFC + kf)*4 + kslot)*32 + nidx;
    short8 bhW = *(const short8*)(wh  + (size_t)c*8);
    short8 blW = *(const short8*)(wlo + (size_t)c*8);
    acc0 = __builtin_amdgcn_mfma_f32_16x16x32_bf16(a0h, bhW, acc0, 0,0,0);
    acc0 = __builtin_amdgcn_mfma_f32_16x16x32_bf16(a0l, bhW, acc0, 0,0,0);
    acc0 = __builtin_amdgcn_mfma_f32_16x16x32_bf16(a0h, blW, acc0, 0,0,0);
    acc1 = __builtin_amdgcn_mfma_f32_16x16x32_bf16(a1h, bhW, acc1, 0,0,0);
    acc1 = __builtin_amdgcn_mfma_f32_16x16x32_bf16(a1l, bhW, acc1, 0,0,0);
    acc1 = __builtin_amdgcn_mfma_f32_16x16x32_bf16(a1h, blW, acc1, 0,0,0);
  }
}

// Clock probe: fixed 240K-cycle dependent-FMA chain. rocprof dur of this
// dispatch = 240e3 / SCLK. 100us at 2.4GHz; 4x longer at 600MHz.
__global__ void clock_probe(float* sink){
  float z = 1e-30f;
  for (int i=0;i<2500;++i){
    #pragma unroll
    for (int j=0;j<24;j++)
      asm volatile("v_fmac_f32 %0, %1, %1" : "+v"(z) : "v"(z));
  }
  if (threadIdx.x==0) sink[0] = z;
}

__global__ __launch_bounds__(256, 1) void lstm_pers(
    const float* __restrict__ x,    const float* __restrict__ h0in, const float* __restrict__ c0in,
    const float* __restrict__ wih0, const float* __restrict__ whh0,
    const float* __restrict__ bih0, const float* __restrict__ bhh0,
    const float* __restrict__ wih1, const float* __restrict__ whh1,
    const float* __restrict__ bih1, const float* __restrict__ bhh1,
    const float* __restrict__ wlin, const float* __restrict__ blin,
    float* __restrict__ out, float* ws)
{
  __shared__ __align__(16) unsigned short wlds_hi[32768];   // 65,536 B
  __shared__ __align__(16) unsigned short wlds_lo[32768];   // 65,536 B
  __shared__ __align__(16) float red[RED_TOT];              //  8,960 B
  const int tid = threadIdx.x, wg = blockIdx.x;
  const int lane = tid & 63;
  const int wid  = tid >> 6;
  const int bgrp = wg & 1;
  const int half = (wg >> 1) & 1;      // 0: layer0, 1: layer1
  const int cg   = wg >> 2;            // 0..63
  const int colbase = cg*8;
  const int khalf = wid & 1;
  const int ntile = wid >> 1;

  unsigned* flags = (unsigned*)ws;                  // 4 domains x 64 lines
  unsigned* F0 = flags + (bgrp*2 + 0)*1024;
  unsigned* F1 = flags + (bgrp*2 + 1)*1024;
  unsigned* myF = half ? F1 : F0;
  unsigned* r0h = ((unsigned*)ws) + 5120;           // planes: [4 slot][2 bgrp][8192]
  unsigned* r0l = r0h + 65536;
  unsigned* r1h = r0h + 131072;
  unsigned* r1l = r0h + 196608;

  unsigned* xsh_s = (unsigned*)(wlds_hi + 20480);   // L0 WGs only (overlay)
  unsigned* xsl_s = (unsigned*)(wlds_lo + 20480);

  // ---- W (bf16 hi/lo) into LDS, once ----
  if (half == 0){
    for (int c = tid; c < 2560; c += 256){
      int kh = c / 1280; int rem = c - kh*1280;
      int kf = rem >> 7; int rem2 = rem & 127;
      int ks = rem2 >> 5; int n = rem2 & 31;
      int kk = kh*320 + kf*32 + ks*8;
      int wrow = (n>>3)*512 + colbase + (n&7);
      const float* src; long off;
      if (kk < 512){ src = whh0; off = (long)wrow*512 + kk; }
      else         { src = wih0; off = (long)wrow*128 + (kk-512); }
      float4 a = *(const float4*)(src + off);
      float4 b = *(const float4*)(src + off + 4);
      short8 hi, lo; cvt8(a, b, hi, lo);
      *(short8*)(wlds_hi + (size_t)c*8) = hi;
      *(short8*)(wlds_lo + (size_t)c*8) = lo;
    }
  } else {
    for (int c = tid; c < 4096; c += 256){
      int kh = c >> 11; int rem = c & 2047;
      int kf = rem >> 7; int rem2 = rem & 127;
      int ks = rem2 >> 5; int n = rem2 & 31;
      int kk = kh*512 + kf*32 + ks*8;
      int wrow = (n>>3)*512 + colbase + (n&7);
      const float* src; long off;
      if (kk < 512){ src = whh1; off = (long)wrow*512 + kk; }
      else         { src = wih1; off = (long)wrow*512 + (kk-512); }
      float4 a = *(const float4*)(src + off);
      float4 b = *(const float4*)(src + off + 4);
      short8 hi, lo; cvt8(a, b, hi, lo);
      *(short8*)(wlds_hi + (size_t)c*8) = hi;
      *(short8*)(wlds_lo + (size_t)c*8) = lo;
    }
  }

  // ---- activation-role state: 1 cell/thread ----
  const int m_l = tid >> 3;            // 0..31 local batch
  const int cl  = tid & 7;             // 0..7 local col
  const int col_own = colbase + cl;
  float biasr[4], cst;
  #pragma unroll
  for (int g=0; g<4; ++g){
    biasr[g] = half ? (bih1[g*512+col_own] + bhh1[g*512+col_own])
                    : (bih0[g*512+col_own] + bhh0[g*512+col_own]);
  }
  cst = c0in[half*32768 + (size_t)(bgrp*32+m_l)*512 + col_own];
  float blin_r = blin[0];
  // producer's fragment-major u32 offset for the (even) pair base c0
  const int c0p   = col_own & ~1;
  const int prodoff = (c0p>>5)*512 + (m_l>>4)*256
                    + (((m_l&15) | (((c0p>>3)&3)<<4))<<2) + ((c0p&7)>>1);

  // ---- y-role state: lane holds wlin[8k..8k+8) ----
  float wl[8];
  {
    const float4* wp = (const float4*)wlin + (lane*2);
    float4 w0 = wp[0], w1 = wp[1];
    wl[0]=w0.x; wl[1]=w0.y; wl[2]=w0.z; wl[3]=w0.w;
    wl[4]=w1.x; wl[5]=w1.y; wl[6]=w1.z; wl[7]=w1.w;
  }
  // y read offset: local batch cgb=cg, lane covers cols lane*8..+8
  const int yoff = (lane>>2)*512 + ((cg>>4)&1)*256
                 + ((((cg&15) | ((lane&3)<<4)))<<2);

  // ---- init h(-1) into slot 0 (fragment-major), domain-restricted ----
  {
    int e = cg*256 + tid;                  // [0, 16384) in (half,bgrp) slab
    if (!(e & 1)){
      int m = e >> 9;                      // 0..31 local batch
      int col = e & 511;                   // even
      const float* src = h0in + half*32768 + (size_t)(bgrp*32+m)*512 + col;
      float v0 = src[0], v1 = src[1];
      unsigned short hA = f2bf(v0), lA = f2bf(v0 - bf2f(hA));
      unsigned short hB = f2bf(v1), lB = f2bf(v1 - bf2f(hB));
      unsigned uh = (unsigned)hA | ((unsigned)hB<<16);
      unsigned ul = (unsigned)lA | ((unsigned)lB<<16);
      int off = (col>>5)*512 + (m>>4)*256
              + (((m&15) | (((col>>3)&3)<<4))<<2) + ((col&7)>>1);
      unsigned* ph = (half ? r1h : r0h) + (0*2 + bgrp)*8192;
      unsigned* pl = (half ? r1l : r0l) + (0*2 + bgrp)*8192;
      st_agent_u32(ph + off, uh);
      st_agent_u32(pl + off, ul);
    }
  }

  // ---- x stage for t=0 (L0 WGs, LDS-local) ----
  if (half == 0){
    int m = tid>>3, dd = (tid&7)*16;
    const float* xp = x + ((size_t)(bgrp*32+m))*65536 + 0*128 + dd;
    float4 v0 = *(const float4*)xp,      v1 = *(const float4*)(xp+4),
           v2 = *(const float4*)(xp+8),  v3 = *(const float4*)(xp+12);
    float vv[16] = {v0.x,v0.y,v0.z,v0.w, v1.x,v1.y,v1.z,v1.w,
                    v2.x,v2.y,v2.z,v2.w, v3.x,v3.y,v3.z,v3.w};
    unsigned uh[8], ul[8];
    #pragma unroll
    for (int j=0;j<8;j++){
      unsigned short hA = f2bf(vv[2*j]),   hB = f2bf(vv[2*j+1]);
      unsigned short lA = f2bf(vv[2*j]-bf2f(hA)), lB = f2bf(vv[2*j+1]-bf2f(hB));
      uh[j] = (unsigned)hA | ((unsigned)hB<<16);
      ul[j] = (unsigned)lA | ((unsigned)lB<<16);
    }
    unsigned* dh = xsh_s + m*68 + (dd>>1);
    unsigned* dl = xsl_s + m*68 + (dd>>1);
    *(uint4*)dh     = make_uint4(uh[0],uh[1],uh[2],uh[3]);
    *(uint4*)(dh+4) = make_uint4(uh[4],uh[5],uh[6],uh[7]);
    *(uint4*)dl     = make_uint4(ul[0],ul[1],ul[2],ul[3]);
    *(uint4*)(dl+4) = make_uint4(ul[4],ul[5],ul[6],ul[7]);
  }

  asm volatile("s_waitcnt vmcnt(0)" ::: "memory");
  __syncthreads();
  if (tid == 0) st_agent_u32(&myF[cg*16], 1u);

  const int m0loc = lane & 15;
  const int kslot = lane >> 4;
  const int nidx  = ntile*16 + (lane & 15);

  if (half == 0){
    // ================= LAYER-0 GROUP =================
    for (int t = 0; t < TT; ++t){
      if (tid < 64){
        const unsigned need0 = (unsigned)(t+1);
        const bool bp = (t >= 4);
        const unsigned need1 = (unsigned)(t-2);
        for(;;){
          bool ok = ldflag(&F0[tid*16]) >= need0;
          if (bp) ok &= (ldflag(&F1[tid*16]) >= need1);
          if (__all(ok)) break;
          __builtin_amdgcn_s_sleep(2);
        }
      }
      __syncthreads();
      __builtin_amdgcn_fence(__ATOMIC_ACQUIRE, "agent");  // inv stale L1/L2

      const unsigned* rAh = r0h + ((t&3)*2 + bgrp)*8192;  // h0(t-1)
      const unsigned* rAl = r0l + ((t&3)*2 + bgrp)*8192;
      const unsigned* xsh_t = xsh_s + (t&1)*2176;
      const unsigned* xsl_t = xsl_s + (t&1)*2176;
      f32x4 acc0 = {0.f,0.f,0.f,0.f}, acc1 = {0.f,0.f,0.f,0.f};
      if (khalf == 0) gates_mfma<10,0,0>(rAh,rAl,0,0,xsh_t,xsl_t,wlds_hi,wlds_lo,lane,m0loc,kslot,nidx,acc0,acc1);
      else            gates_mfma<10,0,1>(rAh,rAl,0,0,xsh_t,xsl_t,wlds_hi,wlds_lo,lane,m0loc,kslot,nidx,acc0,acc1);
      #pragma unroll
      for (int r=0; r<4; ++r){
        int mm = kslot*4 + r;
        red[RED(khalf, mm,    nidx)] = acc0[r];
        red[RED(khalf, 16+mm, nidx)] = acc1[r];
      }
      __syncthreads();

      {
        float g4[4];
        #pragma unroll
        for (int g=0; g<4; ++g){
          int n = g*8 + cl;
          g4[g] = red[RED(0,m_l,n)] + red[RED(1,m_l,n)] + biasr[g];
        }
        float gi = fsigmoid(g4[0]);
        float gf = fsigmoid(g4[1]);
        float gg = ftanh   (g4[2]);
        float go = fsigmoid(g4[3]);
        float c = gf*cst + gi*gg;
        cst = c;
        float h = go * ftanh(c);
        float h_oth = __shfl_xor(h, 1, 64);
        if (!(tid & 1)){
          unsigned short hA = f2bf(h),     lA = f2bf(h - bf2f(hA));
          unsigned short hB = f2bf(h_oth), lB = f2bf(h_oth - bf2f(hB));
          unsigned uh = (unsigned)hA | ((unsigned)hB<<16);
          unsigned ul = (unsigned)lA | ((unsigned)lB<<16);
          int sbase = (((t+1)&3)*2 + bgrp)*8192;
          st_agent_u32(r0h + sbase + prodoff, uh);
          st_agent_u32(r0l + sbase + prodoff, ul);
        }
      }
      asm volatile("s_waitcnt vmcnt(0)" ::: "memory");
      __syncthreads();
      if (tid == 0) st_agent_u32(&F0[cg*16], (unsigned)(t+2));

      if (t+1 < TT){
        int m = tid>>3, dd = (tid&7)*16;
        const float* xp = x + ((size_t)(bgrp*32+m))*65536 + (size_t)(t+1)*128 + dd;
        float4 v0 = *(const float4*)xp,      v1 = *(const float4*)(xp+4),
               v2 = *(const float4*)(xp+8),  v3 = *(const float4*)(xp+12);
        float vv[16] = {v0.x,v0.y,v0.z,v0.w, v1.x,v1.y,v1.z,v1.w,
                        v2.x,v2.y,v2.z,v2.w, v3.x,v3.y,v3.z,v3.w};
        unsigned uh[8], ul[8];
        #pragma unroll
        for (int j=0;j<8;j++){
          unsigned short hA = f2bf(vv[2*j]),   hB = f2bf(vv[2*j+1]);
          unsigned short lA = f2bf(vv[2*j]-bf2f(hA)), lB = f2bf(vv[2*j+1]-bf2f(hB));
          uh[j] = (unsigned)hA | ((unsigned)hB<<16);
          ul[j] = (unsigned)lA | ((unsigned)lB<<16);
        }
        unsigned* dh = xsh_s + ((t+1)&1)*2176 + m*68 + (dd>>1);
        unsigned* dl = xsl_s + ((t+1)&1)*2176 + m*68 + (dd>>1);
        *(uint4*)dh     = make_uint4(uh[0],uh[1],uh[2],uh[3]);
        *(uint4*)(dh+4) = make_uint4(uh[4],uh[5],uh[6],uh[7]);
        *(uint4*)dl     = make_uint4(ul[0],ul[1],ul[2],ul[3]);
        *(uint4*)(dl+4) = make_uint4(ul[4],ul[5],ul[6],ul[7]);
      }
    }
  } else {
    // ================= LAYER-1 GROUP =================
    for (int s = 0; s < TT; ++s){
      if (tid < 64){
        const unsigned need1 = (unsigned)(s+1);
        const unsigned need0 = (unsigned)(s+2);
        for(;;){
          bool ok = (ldflag(&F1[tid*16]) >= need1)
                  & (ldflag(&F0[tid*16]) >= need0);
          if (__all(ok)) break;
          __builtin_amdgcn_s_sleep(2);
        }
      }
      __syncthreads();
      __builtin_amdgcn_fence(__ATOMIC_ACQUIRE, "agent");  // inv stale L1/L2

      // y(s-2): slot (s-1)&3
      if (s >= 2 && cg < 32 && wid == 0){
        int j = s - 2;
        int sbase = (((s-1)&3)*2 + bgrp)*8192;
        uint4 a = *(const uint4*)(r1h + sbase + yoff);
        uint4 b = *(const uint4*)(r1l + sbase + yoff);
        unsigned a4[4] = {a.x,a.y,a.z,a.w}, b4[4] = {b.x,b.y,b.z,b.w};
        float p = 0.f;
        #pragma unroll
        for (int q=0;q<4;q++){
          unsigned qa=a4[q], qb=b4[q];
          float e0 = __uint_as_float(qa<<16) + __uint_as_float(qb<<16);
          float e1 = __uint_as_float(qa & 0xFFFF0000u) + __uint_as_float(qb & 0xFFFF0000u);
          p += e0*wl[2*q] + e1*wl[2*q+1];
        }
        #pragma unroll
        for (int m=1; m<64; m<<=1) p += __shfl_xor(p, m, 64);
        if (lane == 0) st_agent_f(&out[(bgrp*32+cg)*512 + j], p + blin_r);
      }

      const unsigned* rAh = r1h + ((s&3)*2 + bgrp)*8192;      // h1(s-1)
      const unsigned* rAl = r1l + ((s&3)*2 + bgrp)*8192;
      const unsigned* rBh = r0h + (((s+1)&3)*2 + bgrp)*8192;  // h0(s)
      const unsigned* rBl = r0l + (((s+1)&3)*2 + bgrp)*8192;
      f32x4 acc0 = {0.f,0.f,0.f,0.f}, acc1 = {0.f,0.f,0.f,0.f};
      if (khalf == 0) gates_mfma<16,1,0>(rAh,rAl,rBh,rBl,0,0,wlds_hi,wlds_lo,lane,m0loc,kslot,nidx,acc0,acc1);
      else            gates_mfma<16,1,1>(rAh,rAl,rBh,rBl,0,0,wlds_hi,wlds_lo,lane,m0loc,kslot,nidx,acc0,acc1);
      #pragma unroll
      for (int r=0; r<4; ++r){
        int mm = kslot*4 + r;
        red[RED(khalf, mm,    nidx)] = acc0[r];
        red[RED(khalf, 16+mm, nidx)] = acc1[r];
      }
      __syncthreads();

      {
        float g4[4];
        #pragma unroll
        for (int g=0; g<4; ++g){
          int n = g*8 + cl;
          g4[g] = red[RED(0,m_l,n)] + red[RED(1,m_l,n)] + biasr[g];
        }
        float gi = fsigmoid(g4[0]);
        float gf = fsigmoid(g4[1]);
        float gg = ftanh   (g4[2]);
        float go = fsigmoid(g4[3]);
        float c = gf*cst + gi*gg;
        cst = c;
        float h = go * ftanh(c);
        float h_oth = __shfl_xor(h, 1, 64);
        if (!(tid & 1)){
          unsigned short hA = f2bf(h),     lA = f2bf(h - bf2f(hA));
          unsigned short hB = f2bf(h_oth), lB = f2bf(h_oth - bf2f(hB));
          unsigned uh = (unsigned)hA | ((unsigned)hB<<16);
          unsigned ul = (unsigned)lA | ((unsigned)lB<<16);
          int sbase = (((s+1)&3)*2 + bgrp)*8192;
          st_agent_u32(r1h + sbase + prodoff, uh);
          st_agent_u32(r1l + sbase + prodoff, ul);
        }
      }
      asm volatile("s_waitcnt vmcnt(0)" ::: "memory");
      __syncthreads();
      if (tid == 0) st_agent_u32(&F1[cg*16], (unsigned)(s+2));
    }

    // epilogue: y(510), y(511)
    if (tid < 64){
      const unsigned need = (unsigned)(TT+1);
      while (ldflag(&F1[tid*16]) < need) __builtin_amdgcn_s_sleep(2);
    }
    __syncthreads();
    __builtin_amdgcn_fence(__ATOMIC_ACQUIRE, "agent");
    if (cg < 32 && wid == 0){
      #pragma unroll
      for (int e=0; e<2; ++e){
        int j = TT-2+e;
        int sbase = (((j+1)&3)*2 + bgrp)*8192;
        uint4 a = *(const uint4*)(r1h + sbase + yoff);
        uint4 b = *(const uint4*)(r1l + sbase + yoff);
        unsigned a4[4] = {a.x,a.y,a.z,a.w}, b4[4] = {b.x,b.y,b.z,b.w};
        float p = 0.f;
        #pragma unroll
        for (int q=0;q<4;q++){
          unsigned qa=a4[q], qb=b4[q];
          float e0 = __uint_as_float(qa<<16) + __uint_as_float(qb<<16);
          float e1 = __uint_as_float(qa & 0xFFFF0000u) + __uint_as_float(qb & 0xFFFF0000u);
          p += e0*wl[2*q] + e1*wl[2*q+1];
        }
        #pragma unroll
        for (int m=1; m<64; m<<=1) p += __shfl_xor(p, m, 64);
        if (lane == 0) st_agent_f(&out[(bgrp*32+cg)*512 + j], p + blin_r);
      }
    }
  }
}

extern "C" void kernel_launch(void* const* d_in, const int* in_sizes, int n_in,
                              void* d_out, int out_size, void* d_ws, size_t ws_size,
                              hipStream_t stream)
{
  (void)in_sizes; (void)n_in; (void)out_size; (void)ws_size;
  const float* x    = (const float*)d_in[0];
  const float* h0   = (const float*)d_in[1];
  const float* c0   = (const float*)d_in[2];
  const float* wih0 = (const float*)d_in[3];
  const float* whh0 = (const float*)d_in[4];
  const float* bih0 = (const float*)d_in[5];
  const float* bhh0 = (const float*)d_in[6];
  const float* wih1 = (const float*)d_in[7];
  const float* whh1 = (const float*)d_in[8];
  const float* bih1 = (const float*)d_in[9];
  const float* bhh1 = (const float*)d_in[10];
  const float* wlin = (const float*)d_in[11];
  const float* blin = (const float*)d_in[12];
  float* outp = (float*)d_out;
  float* wsp  = (float*)d_ws;

  hipMemsetAsync(d_ws, 0, 18432, stream);

  // clock probe (separate dispatch -> own rocprof row; sink in unused ws gap)
  hipLaunchKernelGGL(clock_probe, dim3(1), dim3(64), 0, stream,
                     wsp + 4608);

  void* args[] = { &x, &h0, &c0, &wih0, &whh0, &bih0, &bhh0,
                   &wih1, &whh1, &bih1, &bhh1, &wlin, &blin, &outp, &wsp };
  hipError_t err = hipLaunchCooperativeKernel((const void*)lstm_pers,
                                              dim3(NWG), dim3(256), args, 0, stream);
  if (err != hipSuccess){
    hipLaunchKernelGGL(lstm_pers, dim3(NWG), dim3(256), 0, stream,
                       x, h0, c0, wih0, whh0, bih0, bhh0,
                       wih1, whh1, bih1, bhh1, wlin, blin, outp, wsp);
  }
}

// Round 14
// 6645.564 us; speedup vs baseline: 1.2663x; 1.0701x over previous
//
#include <hip/hip_runtime.h>
#include <math.h>

// Persistent cooperative 2-layer LSTM. Round 14: dependency-split wave
// scheduling on top of R13 (fragment-major rings, plain b128 ring reads +
// per-step agent-acquire fence, agent write-through stores, decoupled
// (bgrp,layer) domains, single-hop flags).
// Changes vs R13:
//  (1) PER-WAVE polls: L1 khalf1 waves (h0-consumers) poll only F0>=s+2
//      (satisfied early since L0 runs ahead) and compute their K=512 half
//      WHILE khalf0 waves wait on F1>=s+1. In-chain loads halve.
//  (2) y-projection moved to L0 group: y(t-4) computed BEFORE L0's flag
//      store (so L1's slot-overwrite at step t, gated on F0>=t+2 via its
//      khalf1 poll joined at sync1, provably follows the y read).
//      L1 loop = pure recurrence. Epilogue y(508..511) after final F1 wait.
//  (3) Polls spin 8 iters before s_sleep (detect-latency trim).
// Flag = 1 + steps completed. Ring slot for h(j) = (j+1)&3; depth 4.
// Split precision MFMA: gates = Whi*hhi + Whi*hlo + Wlo*hhi (fp32 acc).
//
// ws layout (bytes): flags[4][64] lines @0 (16KB); uints @20480:
//   r0h[4][2][8192], r0l, r1h, r1l (256KB per plane, 1MB).

#define TT 512
#define NWG 256

typedef __attribute__((ext_vector_type(8))) short short8;
typedef __attribute__((ext_vector_type(4))) float f32x4;

#define RED(K,M,N) ((((K)*32+(M))*35)+(N))
#define RED_TOT (2*32*35)

__device__ __forceinline__ float fsigmoid(float v){ return 1.f/(1.f+__expf(-v)); }
__device__ __forceinline__ float ftanh(float v){ return 2.f/(1.f+__expf(-2.f*v)) - 1.f; }

__device__ __forceinline__ unsigned short f2bf(float f){
  unsigned u = __float_as_uint(f);
  unsigned r = ((u>>16)&1u) + 0x7FFFu;
  return (unsigned short)((u + r)>>16);
}
__device__ __forceinline__ float bf2f(unsigned short s){
  return __uint_as_float(((unsigned)s)<<16);
}
__device__ __forceinline__ void cvt8(const float4& a, const float4& b,
                                     short8& hi, short8& lo){
  float v[8] = {a.x,a.y,a.z,a.w,b.x,b.y,b.z,b.w};
  #pragma unroll
  for (int i=0;i<8;i++){
    unsigned short h = f2bf(v[i]);
    unsigned short l = f2bf(v[i] - bf2f(h));
    ((unsigned short*)&hi)[i] = h;
    ((unsigned short*)&lo)[i] = l;
  }
}

__device__ __forceinline__ void st_agent_f(float* p, float v){
  __hip_atomic_store(p, v, __ATOMIC_RELAXED, __HIP_MEMORY_SCOPE_AGENT);
}
__device__ __forceinline__ void st_agent_u32(unsigned* p, unsigned v){
  __hip_atomic_store(p, v, __ATOMIC_RELAXED, __HIP_MEMORY_SCOPE_AGENT);
}
__device__ __forceinline__ unsigned ldflag(const unsigned* p){
  return __hip_atomic_load(p, __ATOMIC_RELAXED, __HIP_MEMORY_SCOPE_AGENT);
}

// Per-wave poll: lane l polls flag line l of a 64-flag domain.
__device__ __forceinline__ void pollwave(const unsigned* F, unsigned need, int lane){
  int it = 0;
  for(;;){
    bool ok = ldflag(&F[lane*16]) >= need;
    if (__all(ok)) break;
    if (++it > 8) __builtin_amdgcn_s_sleep(1);
  }
}
__device__ __forceinline__ void pollwave2(const unsigned* Fa, unsigned na,
                                          const unsigned* Fb, unsigned nb,
                                          bool useb, int lane){
  int it = 0;
  for(;;){
    bool ok = ldflag(&Fa[lane*16]) >= na;
    if (useb) ok &= (ldflag(&Fb[lane*16]) >= nb);
    if (__all(ok)) break;
    if (++it > 8) __builtin_amdgcn_s_sleep(1);
  }
}

// Gate MFMA loop. A-frags: PLAIN coalesced short8 loads from fragment-major
// ring slabs (lane-dense: slab + (chunk*2+sub)*256 + lane*4 uints).
template<int KFC, int LAYER, int KHALF>
__device__ __forceinline__ void gates_mfma(
    const unsigned* __restrict__ rAh, const unsigned* __restrict__ rAl,
    const unsigned* __restrict__ rBh, const unsigned* __restrict__ rBl,
    const unsigned* xsh_t, const unsigned* xsl_t,
    const unsigned short* wh, const unsigned short* wlo,
    int lane, int m0loc, int kslot, int nidx,
    f32x4& acc0, f32x4& acc1)
{
  constexpr int CB = LAYER ? 0 : (KHALF*10);   // chunk base (KB>>5)
  #pragma unroll
  for (int kf=0; kf<KFC; ++kf){
    short8 a0h,a0l,a1h,a1l;
    if (LAYER==0 && KHALF==1 && kf>=6){
      int d2 = (kf-6)*16 + kslot*4;          // uint offset within x row
      a0h = *(const short8*)(xsh_t + m0loc*68 + d2);
      a0l = *(const short8*)(xsl_t + m0loc*68 + d2);
      a1h = *(const short8*)(xsh_t + (m0loc+16)*68 + d2);
      a1l = *(const short8*)(xsl_t + (m0loc+16)*68 + d2);
    } else {
      const unsigned *bh, *bl;
      int chunk;
      if (LAYER==1 && KHALF==1){ bh = rBh; bl = rBl; chunk = kf; }
      else                     { bh = rAh; bl = rAl; chunk = CB + kf; }
      int o0 = chunk*512 + lane*4;           // sub 0 (rows 0..15)
      a0h = *(const short8*)(bh + o0);
      a0l = *(const short8*)(bl + o0);
      a1h = *(const short8*)(bh + o0 + 256); // sub 1 (rows 16..31)
      a1l = *(const short8*)(bl + o0 + 256);
    }
    int c = ((KHALF*KFC + kf)*4 + kslot)*32 + nidx;
    short8 bhW = *(const short8*)(wh  + (size_t)c*8);
    short8 blW = *(const short8*)(wlo + (size_t)c*8);
    acc0 = __builtin_amdgcn_mfma_f32_16x16x32_bf16(a0h, bhW, acc0, 0,0,0);
    acc0 = __builtin_amdgcn_mfma_f32_16x16x32_bf16(a0l, bhW, acc0, 0,0,0);
    acc0 = __builtin_amdgcn_mfma_f32_16x16x32_bf16(a0h, blW, acc0, 0,0,0);
    acc1 = __builtin_amdgcn_mfma_f32_16x16x32_bf16(a1h, bhW, acc1, 0,0,0);
    acc1 = __builtin_amdgcn_mfma_f32_16x16x32_bf16(a1l, bhW, acc1, 0,0,0);
    acc1 = __builtin_amdgcn_mfma_f32_16x16x32_bf16(a1h, blW, acc1, 0,0,0);
  }
}

__global__ __launch_bounds__(256, 1) void lstm_pers(
    const float* __restrict__ x,    const float* __restrict__ h0in, const float* __restrict__ c0in,
    const float* __restrict__ wih0, const float* __restrict__ whh0,
    const float* __restrict__ bih0, const float* __restrict__ bhh0,
    const float* __restrict__ wih1, const float* __restrict__ whh1,
    const float* __restrict__ bih1, const float* __restrict__ bhh1,
    const float* __restrict__ wlin, const float* __restrict__ blin,
    float* __restrict__ out, float* ws)
{
  __shared__ __align__(16) unsigned short wlds_hi[32768];   // 65,536 B
  __shared__ __align__(16) unsigned short wlds_lo[32768];   // 65,536 B
  __shared__ __align__(16) float red[RED_TOT];              //  8,960 B
  const int tid = threadIdx.x, wg = blockIdx.x;
  const int lane = tid & 63;
  const int wid  = tid >> 6;
  const int bgrp = wg & 1;
  const int half = (wg >> 1) & 1;      // 0: layer0, 1: layer1
  const int cg   = wg >> 2;            // 0..63
  const int colbase = cg*8;
  const int khalf = wid & 1;
  const int ntile = wid >> 1;

  unsigned* flags = (unsigned*)ws;                  // 4 domains x 64 lines
  unsigned* F0 = flags + (bgrp*2 + 0)*1024;
  unsigned* F1 = flags + (bgrp*2 + 1)*1024;
  unsigned* myF = half ? F1 : F0;
  unsigned* r0h = ((unsigned*)ws) + 5120;           // planes: [4 slot][2 bgrp][8192]
  unsigned* r0l = r0h + 65536;
  unsigned* r1h = r0h + 131072;
  unsigned* r1l = r0h + 196608;

  unsigned* xsh_s = (unsigned*)(wlds_hi + 20480);   // L0 WGs only (overlay)
  unsigned* xsl_s = (unsigned*)(wlds_lo + 20480);

  // ---- W (bf16 hi/lo) into LDS, once ----
  if (half == 0){
    for (int c = tid; c < 2560; c += 256){
      int kh = c / 1280; int rem = c - kh*1280;
      int kf = rem >> 7; int rem2 = rem & 127;
      int ks = rem2 >> 5; int n = rem2 & 31;
      int kk = kh*320 + kf*32 + ks*8;
      int wrow = (n>>3)*512 + colbase + (n&7);
      const float* src; long off;
      if (kk < 512){ src = whh0; off = (long)wrow*512 + kk; }
      else         { src = wih0; off = (long)wrow*128 + (kk-512); }
      float4 a = *(const float4*)(src + off);
      float4 b = *(const float4*)(src + off + 4);
      short8 hi, lo; cvt8(a, b, hi, lo);
      *(short8*)(wlds_hi + (size_t)c*8) = hi;
      *(short8*)(wlds_lo + (size_t)c*8) = lo;
    }
  } else {
    for (int c = tid; c < 4096; c += 256){
      int kh = c >> 11; int rem = c & 2047;
      int kf = rem >> 7; int rem2 = rem & 127;
      int ks = rem2 >> 5; int n = rem2 & 31;
      int kk = kh*512 + kf*32 + ks*8;
      int wrow = (n>>3)*512 + colbase + (n&7);
      const float* src; long off;
      if (kk < 512){ src = whh1; off = (long)wrow*512 + kk; }
      else         { src = wih1; off = (long)wrow*512 + (kk-512); }
      float4 a = *(const float4*)(src + off);
      float4 b = *(const float4*)(src + off + 4);
      short8 hi, lo; cvt8(a, b, hi, lo);
      *(short8*)(wlds_hi + (size_t)c*8) = hi;
      *(short8*)(wlds_lo + (size_t)c*8) = lo;
    }
  }

  // ---- activation-role state: 1 cell/thread ----
  const int m_l = tid >> 3;            // 0..31 local batch
  const int cl  = tid & 7;             // 0..7 local col
  const int col_own = colbase + cl;
  float biasr[4], cst;
  #pragma unroll
  for (int g=0; g<4; ++g){
    biasr[g] = half ? (bih1[g*512+col_own] + bhh1[g*512+col_own])
                    : (bih0[g*512+col_own] + bhh0[g*512+col_own]);
  }
  cst = c0in[half*32768 + (size_t)(bgrp*32+m_l)*512 + col_own];
  float blin_r = blin[0];
  // producer's fragment-major u32 offset for the (even) pair base c0
  const int c0p   = col_own & ~1;
  const int prodoff = (c0p>>5)*512 + (m_l>>4)*256
                    + (((m_l&15) | (((c0p>>3)&3)<<4))<<2) + ((c0p&7)>>1);

  // ---- y-role state: lane holds wlin[8k..8k+8) ----
  float wl[8];
  {
    const float4* wp = (const float4*)wlin + (lane*2);
    float4 w0 = wp[0], w1 = wp[1];
    wl[0]=w0.x; wl[1]=w0.y; wl[2]=w0.z; wl[3]=w0.w;
    wl[4]=w1.x; wl[5]=w1.y; wl[6]=w1.z; wl[7]=w1.w;
  }
  // y read offset: batch row (bgrp*32+cg), lane covers cols lane*8..+8
  const int yoff = (lane>>2)*512 + ((cg>>4)&1)*256
                 + ((((cg&15) | ((lane&3)<<4)))<<2);

  // ---- init h(-1) into slot 0 (fragment-major), domain-restricted ----
  {
    int e = cg*256 + tid;                  // [0, 16384) in (half,bgrp) slab
    if (!(e & 1)){
      int m = e >> 9;                      // 0..31 local batch
      int col = e & 511;                   // even
      const float* src = h0in + half*32768 + (size_t)(bgrp*32+m)*512 + col;
      float v0 = src[0], v1 = src[1];
      unsigned short hA = f2bf(v0), lA = f2bf(v0 - bf2f(hA));
      unsigned short hB = f2bf(v1), lB = f2bf(v1 - bf2f(hB));
      unsigned uh = (unsigned)hA | ((unsigned)hB<<16);
      unsigned ul = (unsigned)lA | ((unsigned)lB<<16);
      int off = (col>>5)*512 + (m>>4)*256
              + (((m&15) | (((col>>3)&3)<<4))<<2) + ((col&7)>>1);
      unsigned* ph = (half ? r1h : r0h) + (0*2 + bgrp)*8192;
      unsigned* pl = (half ? r1l : r0l) + (0*2 + bgrp)*8192;
      st_agent_u32(ph + off, uh);
      st_agent_u32(pl + off, ul);
    }
  }

  // ---- x stage for t=0 (L0 WGs, LDS-local) ----
  if (half == 0){
    int m = tid>>3, dd = (tid&7)*16;
    const float* xp = x + ((size_t)(bgrp*32+m))*65536 + 0*128 + dd;
    float4 v0 = *(const float4*)xp,      v1 = *(const float4*)(xp+4),
           v2 = *(const float4*)(xp+8),  v3 = *(const float4*)(xp+12);
    float vv[16] = {v0.x,v0.y,v0.z,v0.w, v1.x,v1.y,v1.z,v1.w,
                    v2.x,v2.y,v2.z,v2.w, v3.x,v3.y,v3.z,v3.w};
    unsigned uh[8], ul[8];
    #pragma unroll
    for (int j=0;j<8;j++){
      unsigned short hA = f2bf(vv[2*j]),   hB = f2bf(vv[2*j+1]);
      unsigned short lA = f2bf(vv[2*j]-bf2f(hA)), lB = f2bf(vv[2*j+1]-bf2f(hB));
      uh[j] = (unsigned)hA | ((unsigned)hB<<16);
      ul[j] = (unsigned)lA | ((unsigned)lB<<16);
    }
    unsigned* dh = xsh_s + m*68 + (dd>>1);
    unsigned* dl = xsl_s + m*68 + (dd>>1);
    *(uint4*)dh     = make_uint4(uh[0],uh[1],uh[2],uh[3]);
    *(uint4*)(dh+4) = make_uint4(uh[4],uh[5],uh[6],uh[7]);
    *(uint4*)dl     = make_uint4(ul[0],ul[1],ul[2],ul[3]);
    *(uint4*)(dl+4) = make_uint4(ul[4],ul[5],ul[6],ul[7]);
  }

  asm volatile("s_waitcnt vmcnt(0)" ::: "memory");
  __syncthreads();
  if (tid == 0) st_agent_u32(&myF[cg*16], 1u);

  const int m0loc = lane & 15;
  const int kslot = lane >> 4;
  const int nidx  = ntile*16 + (lane & 15);

  if (half == 0){
    // ================= LAYER-0 GROUP =================
    for (int t = 0; t < TT; ++t){
      // all waves: own h0(t-1) ready + backpressure (write-safety for slot
      // reuse AND y(t-4) input h1(t-4): F1>=t-2 <=> both guaranteed)
      pollwave2(F0, (unsigned)(t+1), F1, (unsigned)(t-2), t>=4, lane);
      __builtin_amdgcn_fence(__ATOMIC_ACQUIRE, "agent");
      __syncthreads();                 // orders prev-iter x-stage writes

      const unsigned* rAh = r0h + ((t&3)*2 + bgrp)*8192;  // h0(t-1)
      const unsigned* rAl = r0l + ((t&3)*2 + bgrp)*8192;
      const unsigned* xsh_t = xsh_s + (t&1)*2176;
      const unsigned* xsl_t = xsl_s + (t&1)*2176;
      f32x4 acc0 = {0.f,0.f,0.f,0.f}, acc1 = {0.f,0.f,0.f,0.f};
      if (khalf == 0) gates_mfma<10,0,0>(rAh,rAl,0,0,xsh_t,xsl_t,wlds_hi,wlds_lo,lane,m0loc,kslot,nidx,acc0,acc1);
      else            gates_mfma<10,0,1>(rAh,rAl,0,0,xsh_t,xsl_t,wlds_hi,wlds_lo,lane,m0loc,kslot,nidx,acc0,acc1);
      #pragma unroll
      for (int r=0; r<4; ++r){
        int mm = kslot*4 + r;
        red[RED(khalf, mm,    nidx)] = acc0[r];
        red[RED(khalf, 16+mm, nidx)] = acc1[r];
      }
      __syncthreads();

      {
        float g4[4];
        #pragma unroll
        for (int g=0; g<4; ++g){
          int n = g*8 + cl;
          g4[g] = red[RED(0,m_l,n)] + red[RED(1,m_l,n)] + biasr[g];
        }
        float gi = fsigmoid(g4[0]);
        float gf = fsigmoid(g4[1]);
        float gg = ftanh   (g4[2]);
        float go = fsigmoid(g4[3]);
        float c = gf*cst + gi*gg;
        cst = c;
        float h = go * ftanh(c);
        float h_oth = __shfl_xor(h, 1, 64);
        if (!(tid & 1)){
          unsigned short hA = f2bf(h),     lA = f2bf(h - bf2f(hA));
          unsigned short hB = f2bf(h_oth), lB = f2bf(h_oth - bf2f(hB));
          unsigned uh = (unsigned)hA | ((unsigned)hB<<16);
          unsigned ul = (unsigned)lA | ((unsigned)lB<<16);
          int sbase = (((t+1)&3)*2 + bgrp)*8192;
          st_agent_u32(r0h + sbase + prodoff, uh);
          st_agent_u32(r0l + sbase + prodoff, ul);
        }
      }

      // y(t-4) BEFORE the flag store: L1's overwrite of h1(t-4)'s slot at
      // its step t is gated (khalf1 poll F0>=t+2, joined at its sync1) on
      // the flag we publish below -> read provably precedes overwrite.
      // Input h1(t-4) visibility: F1>=t-2 (polled above) + this step's fence.
      if (t >= 4 && cg < 32 && wid == 0){
        int j = t - 4;
        int sbase = (((j+1)&3)*2 + bgrp)*8192;
        uint4 a = *(const uint4*)(r1h + sbase + yoff);
        uint4 b = *(const uint4*)(r1l + sbase + yoff);
        unsigned a4[4] = {a.x,a.y,a.z,a.w}, b4[4] = {b.x,b.y,b.z,b.w};
        float p = 0.f;
        #pragma unroll
        for (int q=0;q<4;q++){
          unsigned qa=a4[q], qb=b4[q];
          float e0 = __uint_as_float(qa<<16) + __uint_as_float(qb<<16);
          float e1 = __uint_as_float(qa & 0xFFFF0000u) + __uint_as_float(qb & 0xFFFF0000u);
          p += e0*wl[2*q] + e1*wl[2*q+1];
        }
        #pragma unroll
        for (int m=1; m<64; m<<=1) p += __shfl_xor(p, m, 64);
        if (lane == 0) st_agent_f(&out[(bgrp*32+cg)*512 + j], p + blin_r);
      }

      asm volatile("s_waitcnt vmcnt(0)" ::: "memory");
      __syncthreads();
      if (tid == 0) st_agent_u32(&F0[cg*16], (unsigned)(t+2));

      // x-stage(t+1): off-chain
      if (t+1 < TT){
        int m = tid>>3, dd = (tid&7)*16;
        const float* xp = x + ((size_t)(bgrp*32+m))*65536 + (size_t)(t+1)*128 + dd;
        float4 v0 = *(const float4*)xp,      v1 = *(const float4*)(xp+4),
               v2 = *(const float4*)(xp+8),  v3 = *(const float4*)(xp+12);
        float vv[16] = {v0.x,v0.y,v0.z,v0.w, v1.x,v1.y,v1.z,v1.w,
                        v2.x,v2.y,v2.z,v2.w, v3.x,v3.y,v3.z,v3.w};
        unsigned uh[8], ul[8];
        #pragma unroll
        for (int j=0;j<8;j++){
          unsigned short hA = f2bf(vv[2*j]),   hB = f2bf(vv[2*j+1]);
          unsigned short lA = f2bf(vv[2*j]-bf2f(hA)), lB = f2bf(vv[2*j+1]-bf2f(hB));
          uh[j] = (unsigned)hA | ((unsigned)hB<<16);
          ul[j] = (unsigned)lA | ((unsigned)lB<<16);
        }
        unsigned* dh = xsh_s + ((t+1)&1)*2176 + m*68 + (dd>>1);
        unsigned* dl = xsl_s + ((t+1)&1)*2176 + m*68 + (dd>>1);
        *(uint4*)dh     = make_uint4(uh[0],uh[1],uh[2],uh[3]);
        *(uint4*)(dh+4) = make_uint4(uh[4],uh[5],uh[6],uh[7]);
        *(uint4*)dl     = make_uint4(ul[0],ul[1],ul[2],ul[3]);
        *(uint4*)(dl+4) = make_uint4(ul[4],ul[5],ul[6],ul[7]);
      }
    }

    // ---- epilogue: y(508..511) ----
    if (cg < 32 && wid == 0){
      pollwave(F1, (unsigned)(TT+1), lane);
      __builtin_amdgcn_fence(__ATOMIC_ACQUIRE, "agent");
      #pragma unroll
      for (int e=0; e<4; ++e){
        int j = TT-4+e;
        int sbase = (((j+1)&3)*2 + bgrp)*8192;
        uint4 a = *(const uint4*)(r1h + sbase + yoff);
        uint4 b = *(const uint4*)(r1l + sbase + yoff);
        unsigned a4[4] = {a.x,a.y,a.z,a.w}, b4[4] = {b.x,b.y,b.z,b.w};
        float p = 0.f;
        #pragma unroll
        for (int q=0;q<4;q++){
          unsigned qa=a4[q], qb=b4[q];
          float e0 = __uint_as_float(qa<<16) + __uint_as_float(qb<<16);
          float e1 = __uint_as_float(qa & 0xFFFF0000u) + __uint_as_float(qb & 0xFFFF0000u);
          p += e0*wl[2*q] + e1*wl[2*q+1];
        }
        #pragma unroll
        for (int m=1; m<64; m<<=1) p += __shfl_xor(p, m, 64);
        if (lane == 0) st_agent_f(&out[(bgrp*32+cg)*512 + j], p + blin_r);
      }
    }
  } else {
    // ================= LAYER-1 GROUP: pure recurrence =================
    for (int s = 0; s < TT; ++s){
      // DEPENDENCY-SPLIT poll: khalf1 waves need only h0(s) (early);
      // khalf0 waves need only h1(s-1) (the critical own-loop).
      if (khalf == 1) pollwave(F0, (unsigned)(s+2), lane);
      else            pollwave(F1, (unsigned)(s+1), lane);
      __builtin_amdgcn_fence(__ATOMIC_ACQUIRE, "agent");

      const unsigned* rAh = r1h + ((s&3)*2 + bgrp)*8192;      // h1(s-1)
      const unsigned* rAl = r1l + ((s&3)*2 + bgrp)*8192;
      const unsigned* rBh = r0h + (((s+1)&3)*2 + bgrp)*8192;  // h0(s)
      const unsigned* rBl = r0l + (((s+1)&3)*2 + bgrp)*8192;
      f32x4 acc0 = {0.f,0.f,0.f,0.f}, acc1 = {0.f,0.f,0.f,0.f};
      if (khalf == 0) gates_mfma<16,1,0>(rAh,rAl,rBh,rBl,0,0,wlds_hi,wlds_lo,lane,m0loc,kslot,nidx,acc0,acc1);
      else            gates_mfma<16,1,1>(rAh,rAl,rBh,rBl,0,0,wlds_hi,wlds_lo,lane,m0loc,kslot,nidx,acc0,acc1);
      #pragma unroll
      for (int r=0; r<4; ++r){
        int mm = kslot*4 + r;
        red[RED(khalf, mm,    nidx)] = acc0[r];
        red[RED(khalf, 16+mm, nidx)] = acc1[r];
      }
      __syncthreads();                 // sync1: joins split waves

      {
        float g4[4];
        #pragma unroll
        for (int g=0; g<4; ++g){
          int n = g*8 + cl;
          g4[g] = red[RED(0,m_l,n)] + red[RED(1,m_l,n)] + biasr[g];
        }
        float gi = fsigmoid(g4[0]);
        float gf = fsigmoid(g4[1]);
        float gg = ftanh   (g4[2]);
        float go = fsigmoid(g4[3]);
        float c = gf*cst + gi*gg;
        cst = c;
        float h = go * ftanh(c);
        float h_oth = __shfl_xor(h, 1, 64);
        if (!(tid & 1)){
          unsigned short hA = f2bf(h),     lA = f2bf(h - bf2f(hA));
          unsigned short hB = f2bf(h_oth), lB = f2bf(h_oth - bf2f(hB));
          unsigned uh = (unsigned)hA | ((unsigned)hB<<16);
          unsigned ul = (unsigned)lA | ((unsigned)lB<<16);
          int sbase = (((s+1)&3)*2 + bgrp)*8192;
          st_agent_u32(r1h + sbase + prodoff, uh);
          st_agent_u32(r1l + sbase + prodoff, ul);
        }
      }
      asm volatile("s_waitcnt vmcnt(0)" ::: "memory");
      __syncthreads();                 // sync2
      if (tid == 0) st_agent_u32(&F1[cg*16], (unsigned)(s+2));
    }
  }
}

extern "C" void kernel_launch(void* const* d_in, const int* in_sizes, int n_in,
                              void* d_out, int out_size, void* d_ws, size_t ws_size,
                              hipStream_t stream)
{
  (void)in_sizes; (void)n_in; (void)out_size; (void)ws_size;
  const float* x    = (const float*)d_in[0];
  const float* h0   = (const float*)d_in[1];
  const float* c0   = (const float*)d_in[2];
  const float* wih0 = (const float*)d_in[3];
  const float* whh0 = (const float*)d_in[4];
  const float* bih0 = (const float*)d_in[5];
  const float* bhh0 = (const float*)d_in[6];
  const float* wih1 = (const float*)d_in[7];
  const float* whh1 = (const float*)d_in[8];
  const float* bih1 = (const float*)d_in[9];
  const float* bhh1 = (const float*)d_in[10];
  const float* wlin = (const float*)d_in[11];
  const float* blin = (const float*)d_in[12];
  float* outp = (float*)d_out;
  float* wsp  = (float*)d_ws;

  hipMemsetAsync(d_ws, 0, 18432, stream);

  void* args[] = { &x, &h0, &c0, &wih0, &whh0, &bih0, &bhh0,
                   &wih1, &whh1, &bih1, &bhh1, &wlin, &blin, &outp, &wsp };
  hipError_t err = hipLaunchCooperativeKernel((const void*)lstm_pers,
                                              dim3(NWG), dim3(256), args, 0, stream);
  if (err != hipSuccess){
    hipLaunchKernelGGL(lstm_pers, dim3(NWG), dim3(256), 0, stream,
                       x, h0, c0, wih0, whh0, bih0, bhh0,
                       wih1, whh1, bih1, bhh1, wlin, blin, outp, wsp);
  }
}